// Round 4
// baseline (1747.152 us; speedup 1.0000x reference)
//
#include <hip/hip_runtime.h>

// Problem constants
#define K_CODES 512
#define DIM 80
#define SEQ 4096
#define BATCH 32
#define NVEC (BATCH * SEQ)          // 131072 vectors
#define NELEM ((size_t)NVEC * DIM)  // 10485760 quantized elements
#define KCHUNK 16                   // codes per k-iteration (x reuse factor)

// ws layout: [0..511] int hist | +2048: float sqsum | +4096: float wsq[512]

__global__ void vq_wsq(const float* __restrict__ weight, float* __restrict__ wsq) {
    int k = threadIdx.x;  // 512 threads
    const float* w = weight + (size_t)k * DIM;
    float s = 0.f;
#pragma unroll
    for (int c = 0; c < DIM; ++c) s = fmaf(w[c], w[c], s);
    wsq[k] = s;
}

// One thread per vector. x elements are re-read from L1/L2 once per KCHUNK
// codes (the allocator will not keep 80 floats live — R1-R3 evidence), so we
// maximize reuse per reload: 16 FMAs per x element. Weight rows are
// wave-uniform -> s_load -> SGPR operand (free port). 16 accumulators keep
// VGPR ~< 64 so 8 waves/SIMD hide the L2 latency.
__global__ __launch_bounds__(256, 8) void vq_main(
    const float* __restrict__ x, const float* __restrict__ weight,
    const float* __restrict__ wsq, float* __restrict__ out,
    int* __restrict__ ghist, float* __restrict__ gsq)
{
    __shared__ int lhist[K_CODES];
    __shared__ float lsum[4];
    const int tid = threadIdx.x;
    for (int i = tid; i < K_CODES; i += 256) lhist[i] = 0;
    __syncthreads();

    const int t = blockIdx.x * 256 + tid;   // vector id, grid exactly covers NVEC
    const int b = t >> 12;                  // / 4096
    const int l = t & 4095;
    const float* xp = x + ((size_t)b * DIM) * SEQ + l;

    float bestd = 3.4028235e38f;
    int bestk = 0;

    for (int k = 0; k < K_CODES; k += KCHUNK) {
        const float* w0 = weight + (size_t)k * DIM;  // wave-uniform -> s_load
        float acc[KCHUNK];
#pragma unroll
        for (int j = 0; j < KCHUNK; ++j) acc[j] = 0.f;

#pragma unroll
        for (int cc = 0; cc < DIM; cc += 4) {
            float x0 = xp[(size_t)(cc + 0) * SEQ];
            float x1 = xp[(size_t)(cc + 1) * SEQ];
            float x2 = xp[(size_t)(cc + 2) * SEQ];
            float x3 = xp[(size_t)(cc + 3) * SEQ];
#pragma unroll
            for (int j = 0; j < KCHUNK; ++j) {
                float4 wv = *(const float4*)(w0 + (size_t)j * DIM + cc);
                acc[j] = fmaf(x0, wv.x, acc[j]);
                acc[j] = fmaf(x1, wv.y, acc[j]);
                acc[j] = fmaf(x2, wv.z, acc[j]);
                acc[j] = fmaf(x3, wv.w, acc[j]);
            }
        }

#pragma unroll
        for (int j = 0; j < KCHUNK; ++j) {
            float q = fmaf(-2.f, acc[j], wsq[k + j]);
            if (q < bestd) { bestd = q; bestk = k + j; }
        }
    }

    // histogram (block-local)
    atomicAdd(&lhist[bestk], 1);

    // quantized output + squared-error accumulation
    const float* wb = weight + (size_t)bestk * DIM;  // divergent gather, L2-hit
    float* op = out + 1 + ((size_t)b * DIM) * SEQ + l;
    float sq = 0.f;
#pragma unroll
    for (int c = 0; c < DIM; c += 4) {
        float4 wv = *(const float4*)(wb + c);
        float xa = xp[(size_t)(c + 0) * SEQ];
        float xb = xp[(size_t)(c + 1) * SEQ];
        float xc = xp[(size_t)(c + 2) * SEQ];
        float xd = xp[(size_t)(c + 3) * SEQ];
        float e0 = wv.x - xa;
        float e1 = wv.y - xb;
        float e2 = wv.z - xc;
        float e3 = wv.w - xd;
        sq = fmaf(e0, e0, sq);
        sq = fmaf(e1, e1, sq);
        sq = fmaf(e2, e2, sq);
        sq = fmaf(e3, e3, sq);
        op[(size_t)(c + 0) * SEQ] = wv.x;
        op[(size_t)(c + 1) * SEQ] = wv.y;
        op[(size_t)(c + 2) * SEQ] = wv.z;
        op[(size_t)(c + 3) * SEQ] = wv.w;
    }

    // block loss reduction
#pragma unroll
    for (int off = 32; off; off >>= 1) sq += __shfl_down(sq, off, 64);
    if ((tid & 63) == 0) lsum[tid >> 6] = sq;
    __syncthreads();
    if (tid == 0) {
        float s = lsum[0] + lsum[1] + lsum[2] + lsum[3];
        atomicAdd(gsq, s);
    }

    // flush histogram
    for (int i = tid; i < K_CODES; i += 256) {
        int cnt = lhist[i];
        if (cnt) atomicAdd(&ghist[i], cnt);
    }
}

__global__ void vq_finalize(const int* __restrict__ hist,
                            const float* __restrict__ gsq,
                            float* __restrict__ out, int out_last)
{
    __shared__ float part[8];
    int t = threadIdx.x;  // 512 threads
    float p = (float)hist[t] * (1.0f / (float)NVEC);
    float term = p * logf(p + 1e-10f);
#pragma unroll
    for (int off = 32; off; off >>= 1) term += __shfl_down(term, off, 64);
    if ((t & 63) == 0) part[t >> 6] = term;
    __syncthreads();
    if (t == 0) {
        float s = 0.f;
#pragma unroll
        for (int i = 0; i < 8; ++i) s += part[i];
        out[out_last] = expf(-s);
        out[0] = 1.25f * gsq[0] / (float)NELEM;
    }
}

extern "C" void kernel_launch(void* const* d_in, const int* in_sizes, int n_in,
                              void* d_out, int out_size, void* d_ws, size_t ws_size,
                              hipStream_t stream) {
    const float* x = (const float*)d_in[0];
    const float* weight = (const float*)d_in[1];
    float* out = (float*)d_out;

    int* ghist = (int*)d_ws;
    float* gsq = (float*)((char*)d_ws + 2048);
    float* wsq = (float*)((char*)d_ws + 4096);

    hipMemsetAsync(d_ws, 0, 2052, stream);

    vq_wsq<<<1, K_CODES, 0, stream>>>(weight, wsq);
    vq_main<<<NVEC / 256, 256, 0, stream>>>(x, weight, wsq, out, ghist, gsq);
    vq_finalize<<<1, K_CODES, 0, stream>>>(ghist, gsq, out, out_size - 1);
}

// Round 5
// 309.999 us; speedup vs baseline: 5.6360x; 5.6360x over previous
//
#include <hip/hip_runtime.h>

// Problem constants
#define K_CODES 512
#define DIM 80
#define SEQ 4096
#define NVEC 131072
#define NELEM ((size_t)NVEC * DIM)  // 10485760 quantized elements
#define VPB 64                      // vectors per block
#define KC 128                      // codes per LDS chunk

// ws layout: [0..511] int hist | +2048: float sqsum | +4096: float wsq[512]

__global__ void vq_wsq(const float* __restrict__ weight, float* __restrict__ wsq) {
    int k = threadIdx.x;  // 512 threads
    const float* w = weight + (size_t)k * DIM;
    float s = 0.f;
#pragma unroll
    for (int c = 0; c < DIM; ++c) s = fmaf(w[c], w[c], s);
    wsq[k] = s;
}

// Register-blocked distance GEMM: block = 64 vectors x 512 codes.
// Thread (tv=tid&15, tk=tid>>4) owns a 4-vector x 8-code accumulator tile.
// Per dim-step: 3x ds_read_b128 (heavily lane-broadcast) feeds 32 FMAs.
__global__ __launch_bounds__(256, 2) void vq_main(
    const float* __restrict__ x, const float* __restrict__ weight,
    const float* __restrict__ wsq, float* __restrict__ out,
    int* __restrict__ ghist, float* __restrict__ gsq)
{
    __shared__ float xT[DIM * VPB];       // xT[c*64 + v]  (x's native layout)
    __shared__ float wT[DIM * KC];        // wT[c*128 + k] (transposed codebook chunk)
    __shared__ float rd[VPB * 17];        // cross-tk reduce, padded vs bank conflicts
    __shared__ int   rk[VPB * 17];
    __shared__ int   bk[VPB];
    __shared__ float lsum[4];

    const int tid = threadIdx.x;
    const int tv  = tid & 15;             // vector group: vectors 4*tv .. 4*tv+3
    const int tk  = tid >> 4;             // code group: codes 8*tk .. 8*tk+7 (per chunk)
    const int v0  = blockIdx.x * VPB;
    const int b   = v0 >> 12;             // 64 | 4096 -> whole block same b
    const int l0  = v0 & 4095;
    const float* xbase = x + ((size_t)b * DIM) * SEQ + l0;

    // stage x tile: 80 rows of 64 consecutive floats (coalesced)
    {
        const int lane = tid & 63, w = tid >> 6;
        for (int c = w; c < DIM; c += 4)
            xT[c * VPB + lane] = xbase[(size_t)c * SEQ + lane];
    }

    float bestd[4] = {3.4028235e38f, 3.4028235e38f, 3.4028235e38f, 3.4028235e38f};
    int   bestk[4] = {0, 0, 0, 0};

    for (int kc = 0; kc < K_CODES; kc += KC) {
        __syncthreads();  // previous chunk's readers done (also orders xT stage)
        // stage transposed codebook chunk: wT[c*128+k] = weight[kc+k][c]
        for (int idx = tid; idx < DIM * KC; idx += 256) {
            int k = idx & (KC - 1);
            int c = idx >> 7;
            wT[idx] = weight[(size_t)(kc + k) * DIM + c];
        }
        __syncthreads();

        float acc[4][8];
#pragma unroll
        for (int i = 0; i < 4; ++i)
#pragma unroll
            for (int j = 0; j < 8; ++j) acc[i][j] = 0.f;

#pragma unroll 4
        for (int c = 0; c < DIM; ++c) {
            float4 xv = *(const float4*)&xT[c * VPB + 4 * tv];
            float4 wa = *(const float4*)&wT[c * KC + 8 * tk];
            float4 wb = *(const float4*)&wT[c * KC + 8 * tk + 4];
            acc[0][0] = fmaf(xv.x, wa.x, acc[0][0]);
            acc[1][0] = fmaf(xv.y, wa.x, acc[1][0]);
            acc[2][0] = fmaf(xv.z, wa.x, acc[2][0]);
            acc[3][0] = fmaf(xv.w, wa.x, acc[3][0]);
            acc[0][1] = fmaf(xv.x, wa.y, acc[0][1]);
            acc[1][1] = fmaf(xv.y, wa.y, acc[1][1]);
            acc[2][1] = fmaf(xv.z, wa.y, acc[2][1]);
            acc[3][1] = fmaf(xv.w, wa.y, acc[3][1]);
            acc[0][2] = fmaf(xv.x, wa.z, acc[0][2]);
            acc[1][2] = fmaf(xv.y, wa.z, acc[1][2]);
            acc[2][2] = fmaf(xv.z, wa.z, acc[2][2]);
            acc[3][2] = fmaf(xv.w, wa.z, acc[3][2]);
            acc[0][3] = fmaf(xv.x, wa.w, acc[0][3]);
            acc[1][3] = fmaf(xv.y, wa.w, acc[1][3]);
            acc[2][3] = fmaf(xv.z, wa.w, acc[2][3]);
            acc[3][3] = fmaf(xv.w, wa.w, acc[3][3]);
            acc[0][4] = fmaf(xv.x, wb.x, acc[0][4]);
            acc[1][4] = fmaf(xv.y, wb.x, acc[1][4]);
            acc[2][4] = fmaf(xv.z, wb.x, acc[2][4]);
            acc[3][4] = fmaf(xv.w, wb.x, acc[3][4]);
            acc[0][5] = fmaf(xv.x, wb.y, acc[0][5]);
            acc[1][5] = fmaf(xv.y, wb.y, acc[1][5]);
            acc[2][5] = fmaf(xv.z, wb.y, acc[2][5]);
            acc[3][5] = fmaf(xv.w, wb.y, acc[3][5]);
            acc[0][6] = fmaf(xv.x, wb.z, acc[0][6]);
            acc[1][6] = fmaf(xv.y, wb.z, acc[1][6]);
            acc[2][6] = fmaf(xv.z, wb.z, acc[2][6]);
            acc[3][6] = fmaf(xv.w, wb.z, acc[3][6]);
            acc[0][7] = fmaf(xv.x, wb.w, acc[0][7]);
            acc[1][7] = fmaf(xv.y, wb.w, acc[1][7]);
            acc[2][7] = fmaf(xv.z, wb.w, acc[2][7]);
            acc[3][7] = fmaf(xv.w, wb.w, acc[3][7]);
        }

        // fold this chunk into running argmin (k-ascending, strict <)
#pragma unroll
        for (int j = 0; j < 8; ++j) {
            int kk = kc + 8 * tk + j;
            float ws = wsq[kk];
#pragma unroll
            for (int i = 0; i < 4; ++i) {
                float q = fmaf(-2.f, acc[i][j], ws);
                if (q < bestd[i]) { bestd[i] = q; bestk[i] = kk; }
            }
        }
    }

    // cross-tk reduction: 16 partial argmins per vector
#pragma unroll
    for (int i = 0; i < 4; ++i) {
        rd[(4 * tv + i) * 17 + tk] = bestd[i];
        rk[(4 * tv + i) * 17 + tk] = bestk[i];
    }
    __syncthreads();
    if (tid < VPB) {
        float d = rd[tid * 17]; int k = rk[tid * 17];
        for (int j = 1; j < 16; ++j) {
            float dj = rd[tid * 17 + j]; int kj = rk[tid * 17 + j];
            if (dj < d || (dj == d && kj < k)) { d = dj; k = kj; }
        }
        bk[tid] = k;
        atomicAdd(&ghist[k], 1);
    }
    __syncthreads();

    // epilogue: quantized output + loss, from LDS x and L2-hot codebook
    float sq = 0.f;
    float* op = out + 1 + ((size_t)b * DIM) * SEQ + l0;
#pragma unroll
    for (int m = 0; m < (DIM * VPB) / 256; ++m) {   // 20 elements/thread
        int idx = tid + 256 * m;
        int vv  = idx & 63;
        int c   = idx >> 6;
        float wv = weight[(size_t)bk[vv] * DIM + c];
        float e  = wv - xT[c * VPB + vv];
        sq = fmaf(e, e, sq);
        op[(size_t)c * SEQ + vv] = wv;      // coalesced: consecutive vv
    }

    // block loss reduction
#pragma unroll
    for (int off = 32; off; off >>= 1) sq += __shfl_down(sq, off, 64);
    if ((tid & 63) == 0) lsum[tid >> 6] = sq;
    __syncthreads();
    if (tid == 0) {
        float s = lsum[0] + lsum[1] + lsum[2] + lsum[3];
        atomicAdd(gsq, s);
    }
}

__global__ void vq_finalize(const int* __restrict__ hist,
                            const float* __restrict__ gsq,
                            float* __restrict__ out, int out_last)
{
    __shared__ float part[8];
    int t = threadIdx.x;  // 512 threads
    float p = (float)hist[t] * (1.0f / (float)NVEC);
    float term = p * logf(p + 1e-10f);
#pragma unroll
    for (int off = 32; off; off >>= 1) term += __shfl_down(term, off, 64);
    if ((t & 63) == 0) part[t >> 6] = term;
    __syncthreads();
    if (t == 0) {
        float s = 0.f;
#pragma unroll
        for (int i = 0; i < 8; ++i) s += part[i];
        out[out_last] = expf(-s);
        out[0] = 1.25f * gsq[0] / (float)NELEM;
    }
}

extern "C" void kernel_launch(void* const* d_in, const int* in_sizes, int n_in,
                              void* d_out, int out_size, void* d_ws, size_t ws_size,
                              hipStream_t stream) {
    const float* x = (const float*)d_in[0];
    const float* weight = (const float*)d_in[1];
    float* out = (float*)d_out;

    int* ghist = (int*)d_ws;
    float* gsq = (float*)((char*)d_ws + 2048);
    float* wsq = (float*)((char*)d_ws + 4096);

    hipMemsetAsync(d_ws, 0, 2052, stream);

    vq_wsq<<<1, K_CODES, 0, stream>>>(weight, wsq);
    vq_main<<<NVEC / VPB, 256, 0, stream>>>(x, weight, wsq, out, ghist, gsq);
    vq_finalize<<<1, K_CODES, 0, stream>>>(ghist, gsq, out, out_size - 1);
}

// Round 6
// 196.859 us; speedup vs baseline: 8.8751x; 1.5747x over previous
//
#include <hip/hip_runtime.h>

// Problem constants
#define K_CODES 512
#define DIM 80
#define KPAD 96                      // DIM padded to 3 x K=32 MFMA steps
#define SEQ 4096
#define NVEC 131072
#define NELEM ((size_t)NVEC * DIM)
#define VPB 64                       // vectors per block (4 waves x 16)
#define XROW 216                     // ushorts per LDS x-row: hi[0..95] @0, lo[0..95] @104
                                     // 432B row stride -> 108 words === 12 mod 32 -> 2-way (free) b128 reads

typedef short short8 __attribute__((ext_vector_type(8)));
typedef float f32x4 __attribute__((ext_vector_type(4)));

// ws layout: ghist[512] @0 | gsq @2048 | wsq[512] @4096 | whi[512*96] @8192 | wlo @106496
#define WS_GSQ  2048
#define WS_WSQ  4096
#define WS_WHI  8192
#define WS_WLO  (8192 + K_CODES * KPAD * 2)

__device__ __forceinline__ unsigned short f2bf(float f) {
    union { float f; unsigned int u; } c; c.f = f;
    unsigned int r = c.u + 0x7FFFu + ((c.u >> 16) & 1u);   // RNE
    return (unsigned short)(r >> 16);
}
__device__ __forceinline__ float bf2f(unsigned short h) {
    union { float f; unsigned int u; } c; c.u = ((unsigned int)h) << 16;
    return c.f;
}

__global__ void vq_wsq(const float* __restrict__ weight, float* __restrict__ wsq) {
    int k = threadIdx.x;  // 512 threads
    const float* w = weight + (size_t)k * DIM;
    float s = 0.f;
#pragma unroll
    for (int c = 0; c < DIM; ++c) s = fmaf(w[c], w[c], s);
    wsq[k] = s;
}

// Split codebook into hi/lo bf16, row-major [512][96], zero-padded dims 80..95.
__global__ void vq_wsplit(const float* __restrict__ weight,
                          unsigned short* __restrict__ whi,
                          unsigned short* __restrict__ wlo)
{
    int idx = blockIdx.x * 256 + threadIdx.x;   // grid exactly 512*96/256
    int k = idx / KPAD, c = idx - k * KPAD;
    unsigned short hb = 0, lb = 0;
    if (c < DIM) {
        float f = weight[(size_t)k * DIM + c];
        hb = f2bf(f);
        lb = f2bf(f - bf2f(hb));
    }
    whi[idx] = hb;
    wlo[idx] = lb;
}

// MFMA distance GEMM: block = 64 vectors x 512 codes, 4 waves x 16 vectors.
// A = X tile (vec x dim) from LDS bf16 hi/lo; B = W^T from global whi/wlo
// (per-lane 16B contiguous row loads). dot = hh + hl + lh + ll (4 MFMA terms).
__global__ __launch_bounds__(256, 4) void vq_main(
    const float* __restrict__ x, const float* __restrict__ weight,
    const float* __restrict__ wsq,
    const unsigned short* __restrict__ whi, const unsigned short* __restrict__ wlo,
    float* __restrict__ out, int* __restrict__ ghist, float* __restrict__ gsq)
{
    __shared__ unsigned short xb[VPB * XROW];   // 27648 B
    __shared__ int bk[VPB];
    __shared__ float lsum[4];

    const int tid = threadIdx.x;
    const int v0 = blockIdx.x * VPB;
    const int b  = v0 >> 12;
    const int l0 = v0 & 4095;
    const float* xbase = x + (size_t)b * DIM * SEQ + l0;

    // ---- stage x tile as hi/lo bf16, transposed to [vec][dim] ----
#pragma unroll
    for (int m = 0; m < (VPB * DIM) / 256; ++m) {   // 20 elems/thread
        int idx = tid + 256 * m;
        int v = idx & 63, c = idx >> 6;
        float f = xbase[(size_t)c * SEQ + v];        // coalesced in v
        unsigned short hb = f2bf(f);
        unsigned short lb = f2bf(f - bf2f(hb));
        xb[v * XROW + c] = hb;
        xb[v * XROW + 104 + c] = lb;
    }
#pragma unroll
    for (int m = 0; m < (VPB * (KPAD - DIM)) / 256; ++m) {  // zero-pad c=80..95
        int idx = tid + 256 * m;
        int v = idx & 63, c = DIM + (idx >> 6);
        xb[v * XROW + c] = 0;
        xb[v * XROW + 104 + c] = 0;
    }
    __syncthreads();

    // ---- per-wave A fragments (held in registers for the whole code loop) ----
    const int lane = tid & 63, wid = tid >> 6;
    const int cg = lane >> 4;        // k-group 0..3
    const int cl = lane & 15;        // A row / B col / D col
    const int arow = wid * 16 + cl;  // local vector index for A

    short8 ahi[3], alo[3];
#pragma unroll
    for (int ks = 0; ks < 3; ++ks) {
        ahi[ks] = *(const short8*)&xb[arow * XROW + ks * 32 + cg * 8];
        alo[ks] = *(const short8*)&xb[arow * XROW + 104 + ks * 32 + cg * 8];
    }

    float bestd[4] = {3.4028235e38f, 3.4028235e38f, 3.4028235e38f, 3.4028235e38f};
    int   bestk[4] = {0, 0, 0, 0};

    for (int kt = 0; kt < K_CODES / 16; ++kt) {
        const int code = kt * 16 + cl;
        const unsigned short* wh = whi + (size_t)code * KPAD + cg * 8;
        const unsigned short* wl = wlo + (size_t)code * KPAD + cg * 8;
        short8 bh0 = *(const short8*)(wh);
        short8 bh1 = *(const short8*)(wh + 32);
        short8 bh2 = *(const short8*)(wh + 64);
        short8 bl0 = *(const short8*)(wl);
        short8 bl1 = *(const short8*)(wl + 32);
        short8 bl2 = *(const short8*)(wl + 64);

        f32x4 a0 = {0.f, 0.f, 0.f, 0.f}, a1 = {0.f, 0.f, 0.f, 0.f}, a2 = {0.f, 0.f, 0.f, 0.f};
        a0 = __builtin_amdgcn_mfma_f32_16x16x32_bf16(ahi[0], bh0, a0, 0, 0, 0);
        a1 = __builtin_amdgcn_mfma_f32_16x16x32_bf16(ahi[1], bh1, a1, 0, 0, 0);
        a2 = __builtin_amdgcn_mfma_f32_16x16x32_bf16(ahi[2], bh2, a2, 0, 0, 0);
        a0 = __builtin_amdgcn_mfma_f32_16x16x32_bf16(ahi[0], bl0, a0, 0, 0, 0);
        a1 = __builtin_amdgcn_mfma_f32_16x16x32_bf16(ahi[1], bl1, a1, 0, 0, 0);
        a2 = __builtin_amdgcn_mfma_f32_16x16x32_bf16(ahi[2], bl2, a2, 0, 0, 0);
        a0 = __builtin_amdgcn_mfma_f32_16x16x32_bf16(alo[0], bh0, a0, 0, 0, 0);
        a1 = __builtin_amdgcn_mfma_f32_16x16x32_bf16(alo[1], bh1, a1, 0, 0, 0);
        a2 = __builtin_amdgcn_mfma_f32_16x16x32_bf16(alo[2], bh2, a2, 0, 0, 0);
        a0 = __builtin_amdgcn_mfma_f32_16x16x32_bf16(alo[0], bl0, a0, 0, 0, 0);
        a1 = __builtin_amdgcn_mfma_f32_16x16x32_bf16(alo[1], bl1, a1, 0, 0, 0);
        a2 = __builtin_amdgcn_mfma_f32_16x16x32_bf16(alo[2], bl2, a2, 0, 0, 0);

        float wsqv = wsq[code];
#pragma unroll
        for (int r = 0; r < 4; ++r) {
            float dot = a0[r] + a1[r] + a2[r];
            float q = fmaf(-2.f, dot, wsqv);
            if (q < bestd[r]) { bestd[r] = q; bestk[r] = code; }
        }
    }

    // ---- cross-lane argmin over the 16-code column group (lexicographic) ----
#pragma unroll
    for (int r = 0; r < 4; ++r) {
        float d = bestd[r]; int k = bestk[r];
#pragma unroll
        for (int off = 1; off < 16; off <<= 1) {
            float od = __shfl_xor(d, off, 64);
            int   ok = __shfl_xor(k, off, 64);
            if (od < d || (od == d && ok < k)) { d = od; k = ok; }
        }
        if (cl == 0) {
            int vloc = wid * 16 + cg * 4 + r;    // D row = (lane>>4)*4 + reg
            bk[vloc] = k;
            atomicAdd(&ghist[k], 1);
        }
    }
    __syncthreads();

    // ---- epilogue: quantized output (exact fp32 codebook) + loss ----
    float sq = 0.f;
    float* op = out + 1 + (size_t)b * DIM * SEQ + l0;
#pragma unroll
    for (int m = 0; m < (VPB * DIM) / 256; ++m) {
        int idx = tid + 256 * m;
        int v = idx & 63, c = idx >> 6;
        float wv = weight[(size_t)bk[v] * DIM + c];
        float xv = xbase[(size_t)c * SEQ + v];      // L2-hot re-read
        float e = wv - xv;
        sq = fmaf(e, e, sq);
        op[(size_t)c * SEQ + v] = wv;               // coalesced in v
    }

#pragma unroll
    for (int off = 32; off; off >>= 1) sq += __shfl_down(sq, off, 64);
    if ((tid & 63) == 0) lsum[tid >> 6] = sq;
    __syncthreads();
    if (tid == 0) {
        float s = lsum[0] + lsum[1] + lsum[2] + lsum[3];
        atomicAdd(gsq, s);
    }
}

__global__ void vq_finalize(const int* __restrict__ hist,
                            const float* __restrict__ gsq,
                            float* __restrict__ out, int out_last)
{
    __shared__ float part[8];
    int t = threadIdx.x;  // 512 threads
    float p = (float)hist[t] * (1.0f / (float)NVEC);
    float term = p * logf(p + 1e-10f);
#pragma unroll
    for (int off = 32; off; off >>= 1) term += __shfl_down(term, off, 64);
    if ((t & 63) == 0) part[t >> 6] = term;
    __syncthreads();
    if (t == 0) {
        float s = 0.f;
#pragma unroll
        for (int i = 0; i < 8; ++i) s += part[i];
        out[out_last] = expf(-s);
        out[0] = 1.25f * gsq[0] / (float)NELEM;
    }
}

extern "C" void kernel_launch(void* const* d_in, const int* in_sizes, int n_in,
                              void* d_out, int out_size, void* d_ws, size_t ws_size,
                              hipStream_t stream) {
    const float* x = (const float*)d_in[0];
    const float* weight = (const float*)d_in[1];
    float* out = (float*)d_out;

    int* ghist = (int*)d_ws;
    float* gsq = (float*)((char*)d_ws + WS_GSQ);
    float* wsq = (float*)((char*)d_ws + WS_WSQ);
    unsigned short* whi = (unsigned short*)((char*)d_ws + WS_WHI);
    unsigned short* wlo = (unsigned short*)((char*)d_ws + WS_WLO);

    hipMemsetAsync(d_ws, 0, 2052, stream);

    vq_wsq<<<1, K_CODES, 0, stream>>>(weight, wsq);
    vq_wsplit<<<(K_CODES * KPAD) / 256, 256, 0, stream>>>(weight, whi, wlo);
    vq_main<<<NVEC / VPB, 256, 0, stream>>>(x, weight, wsq, whi, wlo, out, ghist, gsq);
    vq_finalize<<<1, K_CODES, 0, stream>>>(ghist, gsq, out, out_size - 1);
}

// Round 7
// 169.231 us; speedup vs baseline: 10.3241x; 1.1633x over previous
//
#include <hip/hip_runtime.h>

// Problem constants
#define K_CODES 512
#define DIM 80
#define KPAD 96                      // DIM padded to 3 x K=32 MFMA steps
#define SEQ 4096
#define NVEC 131072
#define NELEM ((size_t)NVEC * DIM)
#define VPB 64                       // vectors per block (4 waves x 16)
#define NTILES (K_CODES / 16)        // 32 code tiles

typedef short short8 __attribute__((ext_vector_type(8)));
typedef float f32x4 __attribute__((ext_vector_type(4)));

// ws layout: ghist[512] @0 | gsq @2048 | wsq[512] @4096 | whi[512*96] @8192 | wlo @106496
#define WS_GSQ  2048
#define WS_WSQ  4096
#define WS_WHI  8192
#define WS_WLO  (8192 + K_CODES * KPAD * 2)

__device__ __forceinline__ unsigned short f2bf(float f) {
    union { float f; unsigned int u; } c; c.f = f;
    unsigned int r = c.u + 0x7FFFu + ((c.u >> 16) & 1u);   // RNE
    return (unsigned short)(r >> 16);
}
__device__ __forceinline__ float bf2f(unsigned short h) {
    union { float f; unsigned int u; } c; c.u = ((unsigned int)h) << 16;
    return c.f;
}

__global__ void vq_wsq(const float* __restrict__ weight, float* __restrict__ wsq) {
    int k = threadIdx.x;  // 512 threads
    const float* w = weight + (size_t)k * DIM;
    float s = 0.f;
#pragma unroll
    for (int c = 0; c < DIM; ++c) s = fmaf(w[c], w[c], s);
    wsq[k] = s;
}

// Split codebook into hi/lo bf16, row-major [512][96], zero-padded dims 80..95.
__global__ void vq_wsplit(const float* __restrict__ weight,
                          unsigned short* __restrict__ whi,
                          unsigned short* __restrict__ wlo)
{
    int idx = blockIdx.x * 256 + threadIdx.x;   // grid exactly 512*96/256
    int k = idx / KPAD, c = idx - k * KPAD;
    unsigned short hb = 0, lb = 0;
    if (c < DIM) {
        float f = weight[(size_t)k * DIM + c];
        hb = f2bf(f);
        lb = f2bf(f - bf2f(hb));
    }
    whi[idx] = hb;
    wlo[idx] = lb;
}

// MFMA distance GEMM, B staged through LDS in fragment order.
// Block = 64 vectors x 512 codes, 4 waves x 16 vectors.
// LDS buffer per tile (16 codes): short8 slot g*16+cl, g=(h*3+ks)*4+cg.
__global__ __launch_bounds__(256, 4) void vq_main(
    const float* __restrict__ x, const float* __restrict__ weight,
    const float* __restrict__ wsq,
    const unsigned short* __restrict__ whi, const unsigned short* __restrict__ wlo,
    float* __restrict__ out, int* __restrict__ ghist, float* __restrict__ gsq)
{
    __shared__ short8 bbuf[2][384];   // 12 KB double-buffered B tile
    __shared__ int bk[VPB];
    __shared__ float lsum[4];

    const int tid = threadIdx.x;
    const int v0 = blockIdx.x * VPB;
    const int b  = v0 >> 12;
    const int l0 = v0 & 4095;
    const float* xbase = x + (size_t)b * DIM * SEQ + l0;

    const int lane = tid & 63, wid = tid >> 6;
    const int cg = lane >> 4;        // k-group 0..3
    const int cl = lane & 15;        // A row / B col / D col
    const int arow = wid * 16 + cl;  // local vector index for A

    // ---- build A fragments directly from global (coalesced in v across lanes) ----
    short8 ahi[3], alo[3];
#pragma unroll
    for (int ks = 0; ks < 3; ++ks) {
#pragma unroll
        for (int j = 0; j < 8; ++j) {
            int c = ks * 32 + cg * 8 + j;
            unsigned short hb = 0, lb = 0;
            if (c < DIM) {
                float f = xbase[(size_t)c * SEQ + arow];
                hb = f2bf(f);
                lb = f2bf(f - bf2f(hb));
            }
            ahi[ks][j] = (short)hb;
            alo[ks][j] = (short)lb;
        }
    }

    // ---- per-thread staging slots: element e of the 384-short8 fragment image ----
    // e -> (cl_e = e&15, cg_e = (e>>4)&3, rem = e>>6; ks_e = rem%3, h_e = rem/3)
    const int e0 = tid;                       // every thread
    const int r0m = e0 >> 6;
    const unsigned short* sp0 =
        (r0m >= 3 ? wlo : whi) + (size_t)(e0 & 15) * KPAD + (r0m % 3) * 32 + ((e0 >> 4) & 3) * 8;
    const int e1 = tid + 256;                 // threads 0..127 only
    const int r1m = e1 >> 6;
    const unsigned short* sp1 =
        (r1m >= 3 ? wlo : whi) + (size_t)(e1 & 15) * KPAD + (r1m % 3) * 32 + ((e1 >> 4) & 3) * 8;
    const bool has2 = (tid < 128);

    // prefetch + write tile 0
    short8 s0 = *(const short8*)sp0;
    short8 s1;
    if (has2) s1 = *(const short8*)sp1;
    bbuf[0][e0] = s0;
    if (has2) bbuf[0][e1] = s1;

    float bestd[4] = {3.4028235e38f, 3.4028235e38f, 3.4028235e38f, 3.4028235e38f};
    int   bestk[4] = {0, 0, 0, 0};

    for (int t = 0; t < NTILES; ++t) {
        // issue next tile's global loads early (latency hides under barrier+compute)
        if (t + 1 < NTILES) {
            s0 = *(const short8*)(sp0 + (size_t)(t + 1) * 16 * KPAD);
            if (has2) s1 = *(const short8*)(sp1 + (size_t)(t + 1) * 16 * KPAD);
        }
        __syncthreads();   // tile t's LDS writes visible; tile t-1 readers all done

        const short8* bb = bbuf[t & 1];
        const int base = cg * 16 + cl;
        short8 bh0 = bb[base];
        short8 bh1 = bb[base + 64];
        short8 bh2 = bb[base + 128];
        short8 bl0 = bb[base + 192];
        short8 bl1 = bb[base + 256];
        short8 bl2 = bb[base + 320];

        f32x4 a0 = {0.f, 0.f, 0.f, 0.f}, a1 = {0.f, 0.f, 0.f, 0.f}, a2 = {0.f, 0.f, 0.f, 0.f};
        a0 = __builtin_amdgcn_mfma_f32_16x16x32_bf16(ahi[0], bh0, a0, 0, 0, 0);
        a1 = __builtin_amdgcn_mfma_f32_16x16x32_bf16(ahi[1], bh1, a1, 0, 0, 0);
        a2 = __builtin_amdgcn_mfma_f32_16x16x32_bf16(ahi[2], bh2, a2, 0, 0, 0);
        a0 = __builtin_amdgcn_mfma_f32_16x16x32_bf16(ahi[0], bl0, a0, 0, 0, 0);
        a1 = __builtin_amdgcn_mfma_f32_16x16x32_bf16(ahi[1], bl1, a1, 0, 0, 0);
        a2 = __builtin_amdgcn_mfma_f32_16x16x32_bf16(ahi[2], bl2, a2, 0, 0, 0);
        a0 = __builtin_amdgcn_mfma_f32_16x16x32_bf16(alo[0], bh0, a0, 0, 0, 0);
        a1 = __builtin_amdgcn_mfma_f32_16x16x32_bf16(alo[1], bh1, a1, 0, 0, 0);
        a2 = __builtin_amdgcn_mfma_f32_16x16x32_bf16(alo[2], bh2, a2, 0, 0, 0);
        a0 = __builtin_amdgcn_mfma_f32_16x16x32_bf16(alo[0], bl0, a0, 0, 0, 0);
        a1 = __builtin_amdgcn_mfma_f32_16x16x32_bf16(alo[1], bl1, a1, 0, 0, 0);
        a2 = __builtin_amdgcn_mfma_f32_16x16x32_bf16(alo[2], bl2, a2, 0, 0, 0);

        const int code = t * 16 + cl;
        float wsqv = wsq[code];
#pragma unroll
        for (int r = 0; r < 4; ++r) {
            float dot = a0[r] + a1[r] + a2[r];
            float q = fmaf(-2.f, dot, wsqv);
            if (q < bestd[r]) { bestd[r] = q; bestk[r] = code; }
        }

        // write next tile to the other buffer (safe: readers of it finished pre-barrier)
        if (t + 1 < NTILES) {
            bbuf[(t + 1) & 1][e0] = s0;
            if (has2) bbuf[(t + 1) & 1][e1] = s1;
        }
    }

    // ---- cross-lane argmin over the 16-code column group (lexicographic) ----
#pragma unroll
    for (int r = 0; r < 4; ++r) {
        float d = bestd[r]; int k = bestk[r];
#pragma unroll
        for (int off = 1; off < 16; off <<= 1) {
            float od = __shfl_xor(d, off, 64);
            int   ok = __shfl_xor(k, off, 64);
            if (od < d || (od == d && ok < k)) { d = od; k = ok; }
        }
        if (cl == 0) {
            int vloc = wid * 16 + cg * 4 + r;    // D row = (lane>>4)*4 + reg
            bk[vloc] = k;
            atomicAdd(&ghist[k], 1);
        }
    }
    __syncthreads();

    // ---- epilogue: quantized output (exact fp32 codebook) + loss ----
    float sq = 0.f;
    float* op = out + 1 + (size_t)b * DIM * SEQ + l0;
#pragma unroll
    for (int m = 0; m < (VPB * DIM) / 256; ++m) {
        int idx = tid + 256 * m;
        int v = idx & 63, c = idx >> 6;
        float wv = weight[(size_t)bk[v] * DIM + c];
        float xv = xbase[(size_t)c * SEQ + v];      // L2/L3-hot re-read
        float e = wv - xv;
        sq = fmaf(e, e, sq);
        op[(size_t)c * SEQ + v] = wv;               // coalesced in v
    }

#pragma unroll
    for (int off = 32; off; off >>= 1) sq += __shfl_down(sq, off, 64);
    if ((tid & 63) == 0) lsum[tid >> 6] = sq;
    __syncthreads();
    if (tid == 0) {
        float s = lsum[0] + lsum[1] + lsum[2] + lsum[3];
        atomicAdd(gsq, s);
    }
}

__global__ void vq_finalize(const int* __restrict__ hist,
                            const float* __restrict__ gsq,
                            float* __restrict__ out, int out_last)
{
    __shared__ float part[8];
    int t = threadIdx.x;  // 512 threads
    float p = (float)hist[t] * (1.0f / (float)NVEC);
    float term = p * logf(p + 1e-10f);
#pragma unroll
    for (int off = 32; off; off >>= 1) term += __shfl_down(term, off, 64);
    if ((t & 63) == 0) part[t >> 6] = term;
    __syncthreads();
    if (t == 0) {
        float s = 0.f;
#pragma unroll
        for (int i = 0; i < 8; ++i) s += part[i];
        out[out_last] = expf(-s);
        out[0] = 1.25f * gsq[0] / (float)NELEM;
    }
}

extern "C" void kernel_launch(void* const* d_in, const int* in_sizes, int n_in,
                              void* d_out, int out_size, void* d_ws, size_t ws_size,
                              hipStream_t stream) {
    const float* x = (const float*)d_in[0];
    const float* weight = (const float*)d_in[1];
    float* out = (float*)d_out;

    int* ghist = (int*)d_ws;
    float* gsq = (float*)((char*)d_ws + WS_GSQ);
    float* wsq = (float*)((char*)d_ws + WS_WSQ);
    unsigned short* whi = (unsigned short*)((char*)d_ws + WS_WHI);
    unsigned short* wlo = (unsigned short*)((char*)d_ws + WS_WLO);

    hipMemsetAsync(d_ws, 0, 2052, stream);

    vq_wsq<<<1, K_CODES, 0, stream>>>(weight, wsq);
    vq_wsplit<<<(K_CODES * KPAD) / 256, 256, 0, stream>>>(weight, whi, wlo);
    vq_main<<<NVEC / VPB, 256, 0, stream>>>(x, weight, wsq, whi, wlo, out, ghist, gsq);
    vq_finalize<<<1, K_CODES, 0, stream>>>(ghist, gsq, out, out_size - 1);
}